// Round 1
// baseline (1321.799 us; speedup 1.0000x reference)
//
#include <hip/hip_runtime.h>
#include <cstdint>
#include <cstddef>

// Problem constants (match reference setup_inputs)
#define BB   2
#define SS   1024
#define HID  2048
#define HH   32
#define KVHH 8
#define DD   64
// H*D = 2048, KVH*D = 512

// ---------------------------------------------------------------------------
// Generic tiled fp32 GEMM: C(MxN) = A(MxK) @ B(KxN), all row-major.
// 64x64 tile, BK=16, 256 threads (16x16), 4x4 per thread.
// All dims here are multiples of 64/16 so no edge handling.
// ---------------------------------------------------------------------------
__global__ __launch_bounds__(256) void gemm_f32(
    const float* __restrict__ A, const float* __restrict__ B,
    float* __restrict__ C, int M, int N, int K)
{
    __shared__ float As[16][68];   // [k][m], pad 68 keeps rows 16B-aligned, conflict-light
    __shared__ float Bs[16][64];   // [k][n]

    const int tx = threadIdx.x, ty = threadIdx.y;
    const int tid = ty * 16 + tx;
    const int m0 = blockIdx.y * 64, n0 = blockIdx.x * 64;

    const int arow = tid >> 2;          // 0..63
    const int acol = (tid & 3) << 2;    // 0,4,8,12
    const int brow = tid >> 4;          // 0..15
    const int bcol = (tid & 15) << 2;   // 0..60

    float acc[4][4];
    #pragma unroll
    for (int i = 0; i < 4; ++i)
        #pragma unroll
        for (int j = 0; j < 4; ++j) acc[i][j] = 0.f;

    for (int k0 = 0; k0 < K; k0 += 16) {
        float4 av = *(const float4*)&A[(size_t)(m0 + arow) * K + k0 + acol];
        float4 bv = *(const float4*)&B[(size_t)(k0 + brow) * N + n0 + bcol];
        As[acol + 0][arow] = av.x;
        As[acol + 1][arow] = av.y;
        As[acol + 2][arow] = av.z;
        As[acol + 3][arow] = av.w;
        *(float4*)&Bs[brow][bcol] = bv;
        __syncthreads();

        #pragma unroll
        for (int kk = 0; kk < 16; ++kk) {
            float a[4], b[4];
            #pragma unroll
            for (int i = 0; i < 4; ++i) a[i] = As[kk][ty * 4 + i];
            #pragma unroll
            for (int j = 0; j < 4; ++j) b[j] = Bs[kk][tx * 4 + j];
            #pragma unroll
            for (int i = 0; i < 4; ++i)
                #pragma unroll
                for (int j = 0; j < 4; ++j)
                    acc[i][j] = fmaf(a[i], b[j], acc[i][j]);
        }
        __syncthreads();
    }

    #pragma unroll
    for (int i = 0; i < 4; ++i) {
        float4 v = make_float4(acc[i][0], acc[i][1], acc[i][2], acc[i][3]);
        *(float4*)&C[(size_t)(m0 + ty * 4 + i) * N + n0 + tx * 4] = v;
    }
}

// ---------------------------------------------------------------------------
// In-place RoPE over raw projection output laid out (b, s, nheads, D).
// Thread per (b, s, h, t) with t in [0,32): rotates pair (t, t+32).
// `scale` additionally multiplies the output (used to fold D^-0.5 into q).
// ---------------------------------------------------------------------------
__global__ void rope_inplace(float* __restrict__ raw, int nheads, int nh_shift,
                             float scale)
{
    int idx = blockIdx.x * 256 + threadIdx.x;
    int t = idx & 31;
    int rest = idx >> 5;
    int h = rest & (nheads - 1);
    int rest2 = rest >> nh_shift;
    int s = rest2 & (SS - 1);
    int b = rest2 >> 10;

    float* p = raw + (((size_t)(b * SS + s) * nheads) + h) * DD;
    float x1 = p[t];
    float x2 = p[t + 32];
    // inv_freq = BASE^(-(2t)/D) = 10000^(-t/32)
    float inv = powf(10000.f, -(float)t * (1.f / 32.f));
    float ang = (float)s * inv;
    float c, sn;
    sincosf(ang, &sn, &c);
    p[t]      = (x1 * c - x2 * sn) * scale;
    p[t + 32] = (x2 * c + x1 * sn) * scale;
}

// ---------------------------------------------------------------------------
// Attention. Q layout (b,s,H,D) [pre-scaled by D^-0.5, rope'd], K/V (b,s,KVH,D)
// [k rope'd]. Output AO (b,s,H,D) row-major == (B*S, 2048) for the Wo GEMM.
// One block per (q-tile of 64 rows, head, batch). Two passes over K/V tiles of
// 32 rows: pass 1 -> per-row max m and denom l (online); pass 2 -> recompute
// scores, w = relu(exp(s-m)/l - |off+1|/(qpos+1)), accumulate w @ V.
// ---------------------------------------------------------------------------
__device__ __forceinline__ void compute_scores(
    const float (*Qs)[68], const float (*Ks)[68], const float* __restrict__ bd,
    int q0, int k0p, int tx, int ty, float s[4][2])
{
    #pragma unroll
    for (int i = 0; i < 4; ++i) { s[i][0] = 0.f; s[i][1] = 0.f; }
    #pragma unroll 8
    for (int d = 0; d < 64; ++d) {
        float b0 = Ks[tx * 2 + 0][d];
        float b1 = Ks[tx * 2 + 1][d];
        #pragma unroll
        for (int i = 0; i < 4; ++i) {
            float a = Qs[ty * 4 + i][d];
            s[i][0] = fmaf(a, b0, s[i][0]);
            s[i][1] = fmaf(a, b1, s[i][1]);
        }
    }
    // bias + causal mask. rel = qpos - kpos is always < 1024 here, so the
    // reference's (rel < MAXB) check is vacuous; valid == (rel >= 0).
    #pragma unroll
    for (int i = 0; i < 4; ++i) {
        int qp = q0 + ty * 4 + i;
        #pragma unroll
        for (int jj = 0; jj < 2; ++jj) {
            int kp = k0p + tx * 2 + jj;
            int rel = qp - kp;
            if (rel >= 0) s[i][jj] += bd[rel];
            else          s[i][jj] = -1e30f;
        }
    }
}

__global__ __launch_bounds__(256) void attn_kernel(
    const float* __restrict__ Qp, const float* __restrict__ Kp,
    const float* __restrict__ Vp, const float* __restrict__ bias_diag,
    const float* __restrict__ soff, float* __restrict__ AO)
{
    const int qt = blockIdx.x;     // 0..15
    const int h  = blockIdx.y;     // 0..31
    const int b  = blockIdx.z;     // 0..1
    const int kh = h >> 2;         // GQA group (H/KVH = 4)
    const int tx = threadIdx.x, ty = threadIdx.y;
    const int tid = ty * 16 + tx;
    const int q0 = qt * 64;

    __shared__ float Qs[64][68];
    __shared__ float Ks[32][68];
    __shared__ float Vs[32][68];
    __shared__ float Ws[64][33];
    __shared__ float red[64][16];
    __shared__ float m_s[64], l_s[64], invl_s[64], coff_s[64];

    const float* Qbase = Qp + (size_t)(b * SS + q0) * HID + h * 64;
    const float* Kbase = Kp + (size_t)(b * SS) * (KVHH * DD) + kh * 64;
    const float* Vbase = Vp + (size_t)(b * SS) * (KVHH * DD) + kh * 64;
    const float* bd = bias_diag + h * 1024;

    // Load Q tile (64 x 64), row stride HID in global.
    #pragma unroll
    for (int p = 0; p < 4; ++p) {
        int f = tid + p * 256;
        int row = f >> 4, c4 = (f & 15) << 2;
        float4 v = *(const float4*)&Qbase[(size_t)row * HID + c4];
        Qs[row][c4 + 0] = v.x; Qs[row][c4 + 1] = v.y;
        Qs[row][c4 + 2] = v.z; Qs[row][c4 + 3] = v.w;
    }
    if (tid < 64) { m_s[tid] = -1e30f; l_s[tid] = 0.f; }
    __syncthreads();

    const int ntiles = (qt + 1) * 2;   // 32-wide K tiles covering [0,(qt+1)*64)

    // ---------------- pass 1: m, l ----------------
    for (int j = 0; j < ntiles; ++j) {
        #pragma unroll
        for (int p = 0; p < 2; ++p) {
            int f = tid + p * 256;
            int row = f >> 4, c4 = (f & 15) << 2;
            float4 v = *(const float4*)&Kbase[(size_t)(j * 32 + row) * (KVHH * DD) + c4];
            Ks[row][c4 + 0] = v.x; Ks[row][c4 + 1] = v.y;
            Ks[row][c4 + 2] = v.z; Ks[row][c4 + 3] = v.w;
        }
        __syncthreads();

        float s[4][2];
        compute_scores(Qs, Ks, bd, q0, j * 32, tx, ty, s);

        // row max across the 16 tx threads
        #pragma unroll
        for (int i = 0; i < 4; ++i)
            red[ty * 4 + i][tx] = fmaxf(s[i][0], s[i][1]);
        __syncthreads();
        if (tid < 64) {
            float tm = red[tid][0];
            #pragma unroll
            for (int t2 = 1; t2 < 16; ++t2) tm = fmaxf(tm, red[tid][t2]);
            float mo = m_s[tid];
            float mn = fmaxf(mo, tm);
            l_s[tid] *= __expf(mo - mn);   // exp(-1e30-..) -> 0 on first tile
            m_s[tid] = mn;
        }
        __syncthreads();
        #pragma unroll
        for (int i = 0; i < 4; ++i) {
            float m = m_s[ty * 4 + i];
            red[ty * 4 + i][tx] = __expf(s[i][0] - m) + __expf(s[i][1] - m);
        }
        __syncthreads();
        if (tid < 64) {
            float sum = 0.f;
            #pragma unroll
            for (int t2 = 0; t2 < 16; ++t2) sum += red[tid][t2];
            l_s[tid] += sum;
        }
        __syncthreads();   // also protects Ks before next tile load
    }

    // per-row 1/l and offset/(num_visible)
    if (tid < 64) {
        float offabs = fabsf(soff[h] + 1.f);
        invl_s[tid] = 1.f / l_s[tid];              // l >= 1 (diag term) so safe
        coff_s[tid] = offabs / (float)(q0 + tid + 1);
    }
    __syncthreads();

    // ---------------- pass 2: output ----------------
    float o[4][4];
    #pragma unroll
    for (int i = 0; i < 4; ++i)
        #pragma unroll
        for (int jj = 0; jj < 4; ++jj) o[i][jj] = 0.f;

    for (int j = 0; j < ntiles; ++j) {
        #pragma unroll
        for (int p = 0; p < 2; ++p) {
            int f = tid + p * 256;
            int row = f >> 4, c4 = (f & 15) << 2;
            size_t off = (size_t)(j * 32 + row) * (KVHH * DD) + c4;
            float4 kv = *(const float4*)&Kbase[off];
            float4 vv = *(const float4*)&Vbase[off];
            Ks[row][c4 + 0] = kv.x; Ks[row][c4 + 1] = kv.y;
            Ks[row][c4 + 2] = kv.z; Ks[row][c4 + 3] = kv.w;
            Vs[row][c4 + 0] = vv.x; Vs[row][c4 + 1] = vv.y;
            Vs[row][c4 + 2] = vv.z; Vs[row][c4 + 3] = vv.w;
        }
        __syncthreads();

        float s[4][2];
        compute_scores(Qs, Ks, bd, q0, j * 32, tx, ty, s);

        #pragma unroll
        for (int i = 0; i < 4; ++i) {
            float m = m_s[ty * 4 + i];
            float il = invl_s[ty * 4 + i];
            float cc = coff_s[ty * 4 + i];
            #pragma unroll
            for (int jj = 0; jj < 2; ++jj) {
                float w = __expf(s[i][jj] - m) * il - cc;
                Ws[ty * 4 + i][tx * 2 + jj] = fmaxf(w, 0.f);
            }
        }
        __syncthreads();

        #pragma unroll 4
        for (int kk = 0; kk < 32; ++kk) {
            float w0 = Ws[ty * 4 + 0][kk];
            float w1 = Ws[ty * 4 + 1][kk];
            float w2 = Ws[ty * 4 + 2][kk];
            float w3 = Ws[ty * 4 + 3][kk];
            float v0 = Vs[kk][tx * 4 + 0];
            float v1 = Vs[kk][tx * 4 + 1];
            float v2 = Vs[kk][tx * 4 + 2];
            float v3 = Vs[kk][tx * 4 + 3];
            o[0][0] = fmaf(w0, v0, o[0][0]); o[0][1] = fmaf(w0, v1, o[0][1]);
            o[0][2] = fmaf(w0, v2, o[0][2]); o[0][3] = fmaf(w0, v3, o[0][3]);
            o[1][0] = fmaf(w1, v0, o[1][0]); o[1][1] = fmaf(w1, v1, o[1][1]);
            o[1][2] = fmaf(w1, v2, o[1][2]); o[1][3] = fmaf(w1, v3, o[1][3]);
            o[2][0] = fmaf(w2, v0, o[2][0]); o[2][1] = fmaf(w2, v1, o[2][1]);
            o[2][2] = fmaf(w2, v2, o[2][2]); o[2][3] = fmaf(w2, v3, o[2][3]);
            o[3][0] = fmaf(w3, v0, o[3][0]); o[3][1] = fmaf(w3, v1, o[3][1]);
            o[3][2] = fmaf(w3, v2, o[3][2]); o[3][3] = fmaf(w3, v3, o[3][3]);
        }
        __syncthreads();
    }

    #pragma unroll
    for (int i = 0; i < 4; ++i) {
        float4 v = make_float4(o[i][0], o[i][1], o[i][2], o[i][3]);
        *(float4*)&AO[(size_t)(b * SS + q0 + ty * 4 + i) * HID + h * 64 + tx * 4] = v;
    }
}

// ---------------------------------------------------------------------------
extern "C" void kernel_launch(void* const* d_in, const int* in_sizes, int n_in,
                              void* d_out, int out_size, void* d_ws, size_t ws_size,
                              hipStream_t stream)
{
    const float* hidden    = (const float*)d_in[0];
    // d_in[1] attention_mask: fixed causal tril -> handled analytically
    const float* Wq        = (const float*)d_in[2];
    const float* Wk        = (const float*)d_in[3];
    const float* Wv        = (const float*)d_in[4];
    const float* Wo        = (const float*)d_in[5];
    const float* bias_diag = (const float*)d_in[6];
    const float* soff      = (const float*)d_in[7];
    float* out = (float*)d_out;

    // Workspace layout (floats): qraw 4.19M | kraw 1.05M | vraw 1.05M | AO 4.19M
    float* ws   = (float*)d_ws;
    float* qraw = ws;                                  // (B*S, H*D)
    float* kraw = qraw + (size_t)2048 * 2048;          // (B*S, KVH*D)
    float* vraw = kraw + (size_t)2048 * 512;           // (B*S, KVH*D)
    float* AO   = vraw + (size_t)2048 * 512;           // (B*S, H*D)

    dim3 blk(16, 16);

    // QKV projections
    gemm_f32<<<dim3(32, 32), blk, 0, stream>>>(hidden, Wq, qraw, 2048, 2048, 2048);
    gemm_f32<<<dim3(8, 32),  blk, 0, stream>>>(hidden, Wk, kraw, 2048, 512, 2048);
    gemm_f32<<<dim3(8, 32),  blk, 0, stream>>>(hidden, Wv, vraw, 2048, 512, 2048);

    // RoPE in place; q also gets the D^-0.5 scaling folded in
    rope_inplace<<<dim3((BB * SS * HH * 32) / 256), dim3(256), 0, stream>>>(
        qraw, HH, 5, 0.125f);
    rope_inplace<<<dim3((BB * SS * KVHH * 32) / 256), dim3(256), 0, stream>>>(
        kraw, KVHH, 3, 1.0f);

    // Attention
    attn_kernel<<<dim3(16, 32, 2), blk, 0, stream>>>(
        qraw, kraw, vraw, bias_diag, soff, AO);

    // Output projection
    gemm_f32<<<dim3(32, 32), blk, 0, stream>>>(AO, Wo, out, 2048, 2048, 2048);
}

// Round 2
// 736.968 us; speedup vs baseline: 1.7936x; 1.7936x over previous
//
#include <hip/hip_runtime.h>
#include <cstdint>
#include <cstddef>

// Problem constants
#define BB   2
#define SS   1024
#define HID  2048
#define HH   32
#define KVHH 8
#define DD   64
// Fused QKV projection: N = H*D + 2*KVH*D = 2048 + 512 + 512 = 3072
#define NQKV 3072

typedef __attribute__((ext_vector_type(8))) short bf16x8;
typedef __attribute__((ext_vector_type(4))) float f32x4;

__device__ __forceinline__ unsigned short f2bf(float f) {
    unsigned int u = __float_as_uint(f);
    unsigned int r = (u + 0x7fffu + ((u >> 16) & 1u)) >> 16;
    return (unsigned short)r;
}

// ---------------------------------------------------------------------------
// fp32 -> bf16 convert (vectorized, exact-size grid)
// ---------------------------------------------------------------------------
__global__ void to_bf16(const float* __restrict__ in, unsigned short* __restrict__ outp)
{
    int i = blockIdx.x * 256 + threadIdx.x;
    float4 v = *(const float4*)&in[(size_t)i * 4];
    ushort4 o;
    o.x = f2bf(v.x); o.y = f2bf(v.y); o.z = f2bf(v.z); o.w = f2bf(v.w);
    *(ushort4*)&outp[(size_t)i * 4] = o;
}

// ---------------------------------------------------------------------------
// Transpose + convert: W (K x N fp32, row-major) -> Wt (N x K bf16, row-major)
// block (32,8), tile 32x32 via LDS.
// ---------------------------------------------------------------------------
__global__ void transpose_to_bf16(const float* __restrict__ W,
                                  unsigned short* __restrict__ Wt,
                                  int N, int K)
{
    __shared__ float t[32][33];
    const int n0 = blockIdx.x * 32, k0 = blockIdx.y * 32;
    const int tx = threadIdx.x, ty = threadIdx.y;
    #pragma unroll
    for (int i = 0; i < 4; ++i)
        t[ty * 4 + i][tx] = W[(size_t)(k0 + ty * 4 + i) * N + n0 + tx];
    __syncthreads();
    #pragma unroll
    for (int i = 0; i < 4; ++i)
        Wt[(size_t)(n0 + ty * 4 + i) * K + k0 + tx] = f2bf(t[tx][ty * 4 + i]);
}

// ---------------------------------------------------------------------------
// bf16 MFMA GEMM, B-transposed: C(MxN fp32) = A(MxK bf16) @ Bt(NxK bf16)^T
// 128x128 tile, BK=32 (one 16x16x32 MFMA K-step), 256 threads = 4 waves,
// wave computes 64x64 (4x4 fragments). LDS k-contiguous [128][32], unpadded.
// M,N multiples of 128; K multiple of 32.
// ---------------------------------------------------------------------------
__global__ __launch_bounds__(256) void gemm_bf16_bt(
    const unsigned short* __restrict__ A,
    const unsigned short* __restrict__ Bt,
    float* __restrict__ C, int M, int N, int K)
{
    __shared__ short As[128][32];
    __shared__ short Bs[128][32];

    const int tid  = threadIdx.x;
    const int lane = tid & 63;
    const int wave = tid >> 6;
    const int wm = (wave >> 1) * 64, wn = (wave & 1) * 64;
    const int m0 = blockIdx.y * 128, n0 = blockIdx.x * 128;

    f32x4 acc[4][4] = {};

    const int mrow = lane & 15;
    const int kq   = (lane >> 4) * 8;

    for (int k0 = 0; k0 < K; k0 += 32) {
        #pragma unroll
        for (int p = 0; p < 2; ++p) {
            int ci = tid + p * 256;           // 0..511
            int row = ci >> 2;                // 0..127
            int q = (ci & 3) * 8;             // bf16 element offset in row
            *(int4*)&As[row][q] = *(const int4*)&A [(size_t)(m0 + row) * K + k0 + q];
            *(int4*)&Bs[row][q] = *(const int4*)&Bt[(size_t)(n0 + row) * K + k0 + q];
        }
        __syncthreads();

        bf16x8 af[4], bfr[4];
        #pragma unroll
        for (int i = 0; i < 4; ++i)
            af[i] = *(const bf16x8*)&As[wm + i * 16 + mrow][kq];
        #pragma unroll
        for (int j = 0; j < 4; ++j)
            bfr[j] = *(const bf16x8*)&Bs[wn + j * 16 + mrow][kq];

        #pragma unroll
        for (int i = 0; i < 4; ++i)
            #pragma unroll
            for (int j = 0; j < 4; ++j)
                acc[i][j] = __builtin_amdgcn_mfma_f32_16x16x32_bf16(
                    af[i], bfr[j], acc[i][j], 0, 0, 0);
        __syncthreads();
    }

    // C/D layout: col = lane&15, row = (lane>>4)*4 + reg
    #pragma unroll
    for (int i = 0; i < 4; ++i) {
        int grow = m0 + wm + i * 16 + (lane >> 4) * 4;
        #pragma unroll
        for (int j = 0; j < 4; ++j) {
            int gcol = n0 + wn + j * 16 + (lane & 15);
            #pragma unroll
            for (int rg = 0; rg < 4; ++rg)
                C[(size_t)(grow + rg) * N + gcol] = acc[i][j][rg];
        }
    }
}

// ---------------------------------------------------------------------------
// In-place RoPE on the fused qkv buffer (row stride NQKV).
// Thread per (b, s, h, t), t in [0,32): rotates pair (t, t+32).
// ---------------------------------------------------------------------------
__global__ void rope_inplace(float* __restrict__ qkv, int hoff, int nh_mask,
                             int nh_shift, float scale)
{
    int idx = blockIdx.x * 256 + threadIdx.x;
    int t = idx & 31;
    int rest = idx >> 5;
    int h = rest & nh_mask;
    int rest2 = rest >> nh_shift;
    int s = rest2 & (SS - 1);
    int b = rest2 >> 10;

    float* p = qkv + (size_t)(b * SS + s) * NQKV + hoff + h * 64;
    float x1 = p[t];
    float x2 = p[t + 32];
    float inv = powf(10000.f, -(float)t * (1.f / 32.f));
    float ang = (float)s * inv;
    float c, sn;
    sincosf(ang, &sn, &c);
    p[t]      = (x1 * c - x2 * sn) * scale;
    p[t + 32] = (x2 * c + x1 * sn) * scale;
}

// ---------------------------------------------------------------------------
// Attention (fp32, unchanged math). Reads fused qkv (stride NQKV):
//   q at col h*64 (pre-scaled, rope'd), k at 2048 + kh*64, v at 2560 + kh*64.
// Writes AO in bf16, row-major (B*S, 2048) for the Wo GEMM.
// ---------------------------------------------------------------------------
__device__ __forceinline__ void compute_scores(
    const float (*Qs)[68], const float (*Ks)[68], const float* __restrict__ bd,
    int q0, int k0p, int tx, int ty, float s[4][2])
{
    #pragma unroll
    for (int i = 0; i < 4; ++i) { s[i][0] = 0.f; s[i][1] = 0.f; }
    #pragma unroll 8
    for (int d = 0; d < 64; ++d) {
        float b0 = Ks[tx * 2 + 0][d];
        float b1 = Ks[tx * 2 + 1][d];
        #pragma unroll
        for (int i = 0; i < 4; ++i) {
            float a = Qs[ty * 4 + i][d];
            s[i][0] = fmaf(a, b0, s[i][0]);
            s[i][1] = fmaf(a, b1, s[i][1]);
        }
    }
    #pragma unroll
    for (int i = 0; i < 4; ++i) {
        int qp = q0 + ty * 4 + i;
        #pragma unroll
        for (int jj = 0; jj < 2; ++jj) {
            int kp = k0p + tx * 2 + jj;
            int rel = qp - kp;
            if (rel >= 0) s[i][jj] += bd[rel];   // rel < 1024 always (S==MAXB)
            else          s[i][jj] = -1e30f;
        }
    }
}

__global__ __launch_bounds__(256) void attn_kernel(
    const float* __restrict__ qkv, const float* __restrict__ bias_diag,
    const float* __restrict__ soff, unsigned short* __restrict__ AO)
{
    const int qt = blockIdx.x;
    const int h  = blockIdx.y;
    const int b  = blockIdx.z;
    const int kh = h >> 2;
    const int tx = threadIdx.x, ty = threadIdx.y;
    const int tid = ty * 16 + tx;
    const int q0 = qt * 64;

    __shared__ float Qs[64][68];
    __shared__ float Ks[32][68];
    __shared__ float Vs[32][68];
    __shared__ float Ws[64][33];
    __shared__ float red[64][16];
    __shared__ float m_s[64], l_s[64], invl_s[64], coff_s[64];

    const float* Qbase = qkv + (size_t)(b * SS + q0) * NQKV + h * 64;
    const float* Kbase = qkv + (size_t)(b * SS) * NQKV + 2048 + kh * 64;
    const float* Vbase = qkv + (size_t)(b * SS) * NQKV + 2560 + kh * 64;
    const float* bd = bias_diag + h * 1024;

    #pragma unroll
    for (int p = 0; p < 4; ++p) {
        int f = tid + p * 256;
        int row = f >> 4, c4 = (f & 15) << 2;
        float4 v = *(const float4*)&Qbase[(size_t)row * NQKV + c4];
        Qs[row][c4 + 0] = v.x; Qs[row][c4 + 1] = v.y;
        Qs[row][c4 + 2] = v.z; Qs[row][c4 + 3] = v.w;
    }
    if (tid < 64) { m_s[tid] = -1e30f; l_s[tid] = 0.f; }
    __syncthreads();

    const int ntiles = (qt + 1) * 2;

    // pass 1: m, l
    for (int j = 0; j < ntiles; ++j) {
        #pragma unroll
        for (int p = 0; p < 2; ++p) {
            int f = tid + p * 256;
            int row = f >> 4, c4 = (f & 15) << 2;
            float4 v = *(const float4*)&Kbase[(size_t)(j * 32 + row) * NQKV + c4];
            Ks[row][c4 + 0] = v.x; Ks[row][c4 + 1] = v.y;
            Ks[row][c4 + 2] = v.z; Ks[row][c4 + 3] = v.w;
        }
        __syncthreads();

        float s[4][2];
        compute_scores(Qs, Ks, bd, q0, j * 32, tx, ty, s);

        #pragma unroll
        for (int i = 0; i < 4; ++i)
            red[ty * 4 + i][tx] = fmaxf(s[i][0], s[i][1]);
        __syncthreads();
        if (tid < 64) {
            float tm = red[tid][0];
            #pragma unroll
            for (int t2 = 1; t2 < 16; ++t2) tm = fmaxf(tm, red[tid][t2]);
            float mo = m_s[tid];
            float mn = fmaxf(mo, tm);
            l_s[tid] *= __expf(mo - mn);
            m_s[tid] = mn;
        }
        __syncthreads();
        #pragma unroll
        for (int i = 0; i < 4; ++i) {
            float m = m_s[ty * 4 + i];
            red[ty * 4 + i][tx] = __expf(s[i][0] - m) + __expf(s[i][1] - m);
        }
        __syncthreads();
        if (tid < 64) {
            float sum = 0.f;
            #pragma unroll
            for (int t2 = 0; t2 < 16; ++t2) sum += red[tid][t2];
            l_s[tid] += sum;
        }
        __syncthreads();
    }

    if (tid < 64) {
        float offabs = fabsf(soff[h] + 1.f);
        invl_s[tid] = 1.f / l_s[tid];
        coff_s[tid] = offabs / (float)(q0 + tid + 1);
    }
    __syncthreads();

    // pass 2: output
    float o[4][4];
    #pragma unroll
    for (int i = 0; i < 4; ++i)
        #pragma unroll
        for (int jj = 0; jj < 4; ++jj) o[i][jj] = 0.f;

    for (int j = 0; j < ntiles; ++j) {
        #pragma unroll
        for (int p = 0; p < 2; ++p) {
            int f = tid + p * 256;
            int row = f >> 4, c4 = (f & 15) << 2;
            size_t off = (size_t)(j * 32 + row) * NQKV + c4;
            float4 kv = *(const float4*)&Kbase[off];
            float4 vv = *(const float4*)&Vbase[off];
            Ks[row][c4 + 0] = kv.x; Ks[row][c4 + 1] = kv.y;
            Ks[row][c4 + 2] = kv.z; Ks[row][c4 + 3] = kv.w;
            Vs[row][c4 + 0] = vv.x; Vs[row][c4 + 1] = vv.y;
            Vs[row][c4 + 2] = vv.z; Vs[row][c4 + 3] = vv.w;
        }
        __syncthreads();

        float s[4][2];
        compute_scores(Qs, Ks, bd, q0, j * 32, tx, ty, s);

        #pragma unroll
        for (int i = 0; i < 4; ++i) {
            float m = m_s[ty * 4 + i];
            float il = invl_s[ty * 4 + i];
            float cc = coff_s[ty * 4 + i];
            #pragma unroll
            for (int jj = 0; jj < 2; ++jj) {
                float w = __expf(s[i][jj] - m) * il - cc;
                Ws[ty * 4 + i][tx * 2 + jj] = fmaxf(w, 0.f);
            }
        }
        __syncthreads();

        #pragma unroll 4
        for (int kk = 0; kk < 32; ++kk) {
            float w0 = Ws[ty * 4 + 0][kk];
            float w1 = Ws[ty * 4 + 1][kk];
            float w2 = Ws[ty * 4 + 2][kk];
            float w3 = Ws[ty * 4 + 3][kk];
            float v0 = Vs[kk][tx * 4 + 0];
            float v1 = Vs[kk][tx * 4 + 1];
            float v2 = Vs[kk][tx * 4 + 2];
            float v3 = Vs[kk][tx * 4 + 3];
            o[0][0] = fmaf(w0, v0, o[0][0]); o[0][1] = fmaf(w0, v1, o[0][1]);
            o[0][2] = fmaf(w0, v2, o[0][2]); o[0][3] = fmaf(w0, v3, o[0][3]);
            o[1][0] = fmaf(w1, v0, o[1][0]); o[1][1] = fmaf(w1, v1, o[1][1]);
            o[1][2] = fmaf(w1, v2, o[1][2]); o[1][3] = fmaf(w1, v3, o[1][3]);
            o[2][0] = fmaf(w2, v0, o[2][0]); o[2][1] = fmaf(w2, v1, o[2][1]);
            o[2][2] = fmaf(w2, v2, o[2][2]); o[2][3] = fmaf(w2, v3, o[2][3]);
            o[3][0] = fmaf(w3, v0, o[3][0]); o[3][1] = fmaf(w3, v1, o[3][1]);
            o[3][2] = fmaf(w3, v2, o[3][2]); o[3][3] = fmaf(w3, v3, o[3][3]);
        }
        __syncthreads();
    }

    #pragma unroll
    for (int i = 0; i < 4; ++i) {
        ushort4 st;
        st.x = f2bf(o[i][0]); st.y = f2bf(o[i][1]);
        st.z = f2bf(o[i][2]); st.w = f2bf(o[i][3]);
        *(ushort4*)&AO[(size_t)(b * SS + q0 + ty * 4 + i) * 2048 + h * 64 + tx * 4] = st;
    }
}

// ---------------------------------------------------------------------------
extern "C" void kernel_launch(void* const* d_in, const int* in_sizes, int n_in,
                              void* d_out, int out_size, void* d_ws, size_t ws_size,
                              hipStream_t stream)
{
    const float* hidden    = (const float*)d_in[0];
    const float* Wq        = (const float*)d_in[2];
    const float* Wk        = (const float*)d_in[3];
    const float* Wv        = (const float*)d_in[4];
    const float* Wo        = (const float*)d_in[5];
    const float* bias_diag = (const float*)d_in[6];
    const float* soff      = (const float*)d_in[7];
    float* out = (float*)d_out;

    // Workspace layout (bytes):
    //   hidden_bf / AO_bf (aliased) : 2048*2048*2  =  8.39 MB
    //   WqkvT bf16 [3072][2048]     : 3072*2048*2  = 12.58 MB
    //   WoT   bf16 [2048][2048]     : 2048*2048*2  =  8.39 MB
    //   qkv   fp32 [2048][3072]     : 2048*3072*4  = 25.17 MB
    // total ~54.5 MB
    char* wsb = (char*)d_ws;
    unsigned short* hidden_bf = (unsigned short*)wsb;            // also AO_bf later
    unsigned short* WqkvT     = (unsigned short*)(wsb + (size_t)2048 * 2048 * 2);
    unsigned short* WoT       = (unsigned short*)(wsb + (size_t)2048 * 2048 * 2 + (size_t)3072 * 2048 * 2);
    float*          qkv       = (float*)(wsb + (size_t)2048 * 2048 * 2 + (size_t)3072 * 2048 * 2 + (size_t)2048 * 2048 * 2);
    unsigned short* AO_bf     = hidden_bf;   // alias: hidden_bf dead after proj GEMM

    // 1. hidden -> bf16
    to_bf16<<<dim3(2048 * 2048 / 4 / 256), dim3(256), 0, stream>>>(hidden, hidden_bf);

    // 2. weight transposes+convert into fused [3072][2048] and WoT
    transpose_to_bf16<<<dim3(64, 64), dim3(32, 8), 0, stream>>>(Wq, WqkvT, 2048, 2048);
    transpose_to_bf16<<<dim3(16, 64), dim3(32, 8), 0, stream>>>(Wk, WqkvT + (size_t)2048 * 2048, 512, 2048);
    transpose_to_bf16<<<dim3(16, 64), dim3(32, 8), 0, stream>>>(Wv, WqkvT + (size_t)2560 * 2048, 512, 2048);
    transpose_to_bf16<<<dim3(64, 64), dim3(32, 8), 0, stream>>>(Wo, WoT, 2048, 2048);

    // 3. fused QKV projection: qkv[2048][3072] = hidden_bf @ WqkvT^T
    gemm_bf16_bt<<<dim3(NQKV / 128, 2048 / 128), dim3(256), 0, stream>>>(
        hidden_bf, WqkvT, qkv, 2048, NQKV, 2048);

    // 4. RoPE (q gets D^-0.5 folded in)
    rope_inplace<<<dim3(BB * SS * HH * 32 / 256), dim3(256), 0, stream>>>(
        qkv, 0, HH - 1, 5, 0.125f);
    rope_inplace<<<dim3(BB * SS * KVHH * 32 / 256), dim3(256), 0, stream>>>(
        qkv, 2048, KVHH - 1, 3, 1.0f);

    // 5. attention -> AO (bf16)
    attn_kernel<<<dim3(16, HH, BB), dim3(16, 16), 0, stream>>>(
        qkv, bias_diag, soff, AO_bf);

    // 6. output projection: out = AO_bf @ WoT^T (fp32 out)
    gemm_bf16_bt<<<dim3(2048 / 128, 2048 / 128), dim3(256), 0, stream>>>(
        AO_bf, WoT, out, 2048, 2048, 2048);
}

// Round 3
// 316.625 us; speedup vs baseline: 4.1747x; 2.3276x over previous
//
#include <hip/hip_runtime.h>
#include <cstdint>
#include <cstddef>

// Problem constants
#define BB   2
#define SS   1024
#define HID  2048
#define HH   32
#define KVHH 8
#define DD   64
#define NQKV 3072   // fused QKV projection width: 2048 + 512 + 512
#define QKW  2560   // qk_bf row width: 2048 q + 512 k

typedef __attribute__((ext_vector_type(8))) short bf16x8;
typedef __attribute__((ext_vector_type(4))) float f32x4;

__device__ __forceinline__ unsigned short f2bf(float f) {
    unsigned int u = __float_as_uint(f);
    unsigned int r = (u + 0x7fffu + ((u >> 16) & 1u)) >> 16;
    return (unsigned short)r;
}

// ---------------------------------------------------------------------------
// fp32 -> bf16 convert
// ---------------------------------------------------------------------------
__global__ void to_bf16(const float* __restrict__ in, unsigned short* __restrict__ outp)
{
    int i = blockIdx.x * 256 + threadIdx.x;
    float4 v = *(const float4*)&in[(size_t)i * 4];
    ushort4 o;
    o.x = f2bf(v.x); o.y = f2bf(v.y); o.z = f2bf(v.z); o.w = f2bf(v.w);
    *(ushort4*)&outp[(size_t)i * 4] = o;
}

// ---------------------------------------------------------------------------
// Transpose + convert: W (K x N fp32) -> Wt (N x K bf16)
// ---------------------------------------------------------------------------
__global__ void transpose_to_bf16(const float* __restrict__ W,
                                  unsigned short* __restrict__ Wt,
                                  int N, int K)
{
    __shared__ float t[32][33];
    const int n0 = blockIdx.x * 32, k0 = blockIdx.y * 32;
    const int tx = threadIdx.x, ty = threadIdx.y;
    #pragma unroll
    for (int i = 0; i < 4; ++i)
        t[ty * 4 + i][tx] = W[(size_t)(k0 + ty * 4 + i) * N + n0 + tx];
    __syncthreads();
    #pragma unroll
    for (int i = 0; i < 4; ++i)
        Wt[(size_t)(n0 + ty * 4 + i) * K + k0 + tx] = f2bf(t[tx][ty * 4 + i]);
}

// ---------------------------------------------------------------------------
// bf16 MFMA GEMM, B-transposed: C(MxN fp32) = A(MxK bf16) @ Bt(NxK bf16)^T
// ---------------------------------------------------------------------------
__global__ __launch_bounds__(256) void gemm_bf16_bt(
    const unsigned short* __restrict__ A,
    const unsigned short* __restrict__ Bt,
    float* __restrict__ C, int M, int N, int K)
{
    __shared__ short As[128][32];
    __shared__ short Bs[128][32];

    const int tid  = threadIdx.x;
    const int lane = tid & 63;
    const int wave = tid >> 6;
    const int wm = (wave >> 1) * 64, wn = (wave & 1) * 64;
    const int m0 = blockIdx.y * 128, n0 = blockIdx.x * 128;

    f32x4 acc[4][4] = {};

    const int mrow = lane & 15;
    const int kq   = (lane >> 4) * 8;

    for (int k0 = 0; k0 < K; k0 += 32) {
        #pragma unroll
        for (int p = 0; p < 2; ++p) {
            int ci = tid + p * 256;
            int row = ci >> 2;
            int q = (ci & 3) * 8;
            *(int4*)&As[row][q] = *(const int4*)&A [(size_t)(m0 + row) * K + k0 + q];
            *(int4*)&Bs[row][q] = *(const int4*)&Bt[(size_t)(n0 + row) * K + k0 + q];
        }
        __syncthreads();

        bf16x8 af[4], bfr[4];
        #pragma unroll
        for (int i = 0; i < 4; ++i)
            af[i] = *(const bf16x8*)&As[wm + i * 16 + mrow][kq];
        #pragma unroll
        for (int j = 0; j < 4; ++j)
            bfr[j] = *(const bf16x8*)&Bs[wn + j * 16 + mrow][kq];

        #pragma unroll
        for (int i = 0; i < 4; ++i)
            #pragma unroll
            for (int j = 0; j < 4; ++j)
                acc[i][j] = __builtin_amdgcn_mfma_f32_16x16x32_bf16(
                    af[i], bfr[j], acc[i][j], 0, 0, 0);
        __syncthreads();
    }

    #pragma unroll
    for (int i = 0; i < 4; ++i) {
        int grow = m0 + wm + i * 16 + (lane >> 4) * 4;
        #pragma unroll
        for (int j = 0; j < 4; ++j) {
            int gcol = n0 + wn + j * 16 + (lane & 15);
            #pragma unroll
            for (int rg = 0; rg < 4; ++rg)
                C[(size_t)(grow + rg) * N + gcol] = acc[i][j][rg];
        }
    }
}

// ---------------------------------------------------------------------------
// RoPE + fp32->bf16 for q (scaled by D^-0.5) and k, out of fused qkv fp32.
// qk_bf: [B*S][2560] bf16 (q cols 0..2047, k cols 2048..2559).
// grid (40 regions, 256 row-groups), block 256: t = tid&31, rloc = tid>>5.
// ---------------------------------------------------------------------------
__global__ void rope_convert(const float* __restrict__ qkv,
                             unsigned short* __restrict__ qk_bf)
{
    const int r = blockIdx.x;                 // 0..39: heads q(0..31), k(32..39)
    const int t = threadIdx.x & 31;
    const int row = blockIdx.y * 8 + (threadIdx.x >> 5);   // 0..2047
    const int s = row & (SS - 1);

    const float* src = qkv + (size_t)row * NQKV + r * 64;
    unsigned short* dst = qk_bf + (size_t)row * QKW + r * 64;

    float x1 = src[t];
    float x2 = src[t + 32];
    float inv = powf(10000.f, -(float)t * (1.f / 32.f));
    float ang = (float)s * inv;
    float c, sn;
    sincosf(ang, &sn, &c);
    float scale = (r < 32) ? 0.125f : 1.0f;
    dst[t]      = f2bf((x1 * c - x2 * sn) * scale);
    dst[t + 32] = f2bf((x2 * c + x1 * sn) * scale);
}

// ---------------------------------------------------------------------------
// V transpose + convert: qkv[b*S+s][2560+c] fp32 -> v_t[(b*512+c)][s] bf16.
// ---------------------------------------------------------------------------
__global__ void v_transpose(const float* __restrict__ qkv,
                            unsigned short* __restrict__ v_t)
{
    __shared__ float tls[32][33];
    const int c0 = blockIdx.x * 32;
    const int s0 = blockIdx.y * 32;
    const int b  = blockIdx.z;
    const int tx = threadIdx.x, ty = threadIdx.y;
    #pragma unroll
    for (int i = 0; i < 4; ++i)
        tls[ty * 4 + i][tx] =
            qkv[(size_t)(b * SS + s0 + ty * 4 + i) * NQKV + 2560 + c0 + tx];
    __syncthreads();
    #pragma unroll
    for (int i = 0; i < 4; ++i)
        v_t[(size_t)(b * 512 + c0 + ty * 4 + i) * SS + s0 + tx] =
            f2bf(tls[tx][ty * 4 + i]);
}

// ---------------------------------------------------------------------------
// MFMA flash attention, two-pass (exact softmax without max subtraction:
// scores are bounded ~|s|<8 by construction). One block per (qtile64, h, b).
// Pass 1: l = sum exp(s+bias) via QK^T MFMA. Pass 2: recompute scores,
// w = relu(exp - c*l) -> bf16 -> PV MFMA; epilogue divides by l.
// ---------------------------------------------------------------------------
__global__ __launch_bounds__(256) void attn_mfma(
    const unsigned short* __restrict__ qk_bf,   // [2048][2560]
    const unsigned short* __restrict__ v_t,     // [1024][1024] (b*512+c rows)
    const float* __restrict__ bias_diag,
    const float* __restrict__ soff,
    unsigned short* __restrict__ AO)            // [2048][2048] bf16
{
    const int qt = 15 - (int)blockIdx.x;        // big tiles dispatched first
    const int h  = blockIdx.y;
    const int b  = blockIdx.z;
    const int kh = h >> 2;
    const int tid  = threadIdx.x;
    const int lane = tid & 63;
    const int wave = tid >> 6;
    const int quad = lane >> 4;
    const int l15  = lane & 15;
    const int kq   = quad * 8;
    const int q0   = qt * 64;

    __shared__ short Qs[64][72];
    __shared__ short Ks[64][72];
    __shared__ short Vt[64][72];
    __shared__ short Ws[64][72];
    __shared__ float bd_s[1024];

    for (int i = tid; i < 1024; i += 256) bd_s[i] = bias_diag[h * 1024 + i];

    {   // stage Q tile (rows q0.., cols h*64..)
        const unsigned short* Qg = qk_bf + (size_t)(b * SS + q0) * QKW + h * 64;
        #pragma unroll
        for (int p = 0; p < 2; ++p) {
            int t = tid + p * 256;
            int row = t >> 3, cq = (t & 7) * 8;
            *(int4*)&Qs[row][cq] = *(const int4*)&Qg[(size_t)row * QKW + cq];
        }
    }

    const int ntiles = qt + 1;
    const unsigned short* Kg = qk_bf + (size_t)(b * SS) * QKW + 2048 + kh * 64;
    const unsigned short* Vg = v_t + (size_t)(b * 512 + kh * 64) * SS;
    const int qrow = q0 + wave * 16 + quad * 4;   // first of this lane's 4 rows

    float lp[4] = {0.f, 0.f, 0.f, 0.f};

    // ---------------- pass 1: l ----------------
    for (int j = 0; j < ntiles; ++j) {
        __syncthreads();
        #pragma unroll
        for (int p = 0; p < 2; ++p) {
            int t = tid + p * 256;
            int row = t >> 3, cq = (t & 7) * 8;
            *(int4*)&Ks[row][cq] =
                *(const int4*)&Kg[(size_t)(j * 64 + row) * QKW + cq];
        }
        __syncthreads();

        f32x4 acc[4] = {};
        #pragma unroll
        for (int s = 0; s < 2; ++s) {
            bf16x8 af = *(const bf16x8*)&Qs[wave * 16 + l15][s * 32 + kq];
            #pragma unroll
            for (int nb = 0; nb < 4; ++nb) {
                bf16x8 bf = *(const bf16x8*)&Ks[nb * 16 + l15][s * 32 + kq];
                acc[nb] = __builtin_amdgcn_mfma_f32_16x16x32_bf16(
                    af, bf, acc[nb], 0, 0, 0);
            }
        }
        #pragma unroll
        for (int nb = 0; nb < 4; ++nb) {
            int kp = j * 64 + nb * 16 + l15;
            #pragma unroll
            for (int r = 0; r < 4; ++r) {
                int rel = qrow + r - kp;
                if (rel >= 0) lp[r] += __expf(acc[nb][r] + bd_s[rel]);
            }
        }
    }

    // reduce lp across the 16 lanes of each quad
    #pragma unroll
    for (int off = 1; off < 16; off <<= 1)
        #pragma unroll
        for (int r = 0; r < 4; ++r)
            lp[r] += __shfl_xor(lp[r], off, 64);

    float cl[4], invl[4];
    {
        float offa = fabsf(soff[h] + 1.f);
        #pragma unroll
        for (int r = 0; r < 4; ++r) {
            invl[r] = 1.f / lp[r];
            cl[r] = offa / (float)(qrow + r + 1) * lp[r];
        }
    }

    // ---------------- pass 2: output ----------------
    f32x4 oacc[4] = {};
    for (int j = 0; j < ntiles; ++j) {
        __syncthreads();
        #pragma unroll
        for (int p = 0; p < 2; ++p) {
            int t = tid + p * 256;
            int row = t >> 3, cq = (t & 7) * 8;
            *(int4*)&Ks[row][cq] =
                *(const int4*)&Kg[(size_t)(j * 64 + row) * QKW + cq];
            *(int4*)&Vt[row][cq] =
                *(const int4*)&Vg[(size_t)row * SS + j * 64 + cq];
        }
        __syncthreads();

        f32x4 acc[4] = {};
        #pragma unroll
        for (int s = 0; s < 2; ++s) {
            bf16x8 af = *(const bf16x8*)&Qs[wave * 16 + l15][s * 32 + kq];
            #pragma unroll
            for (int nb = 0; nb < 4; ++nb) {
                bf16x8 bf = *(const bf16x8*)&Ks[nb * 16 + l15][s * 32 + kq];
                acc[nb] = __builtin_amdgcn_mfma_f32_16x16x32_bf16(
                    af, bf, acc[nb], 0, 0, 0);
            }
        }
        // w = relu(exp(s) - c*l) in C-layout -> Ws (wave-private rows)
        #pragma unroll
        for (int nb = 0; nb < 4; ++nb) {
            int kp = j * 64 + nb * 16 + l15;
            #pragma unroll
            for (int r = 0; r < 4; ++r) {
                int rel = qrow + r - kp;
                float w = 0.f;
                if (rel >= 0)
                    w = fmaxf(__expf(acc[nb][r] + bd_s[rel]) - cl[r], 0.f);
                Ws[wave * 16 + quad * 4 + r][nb * 16 + l15] = (short)f2bf(w);
            }
        }
        // PV: A = Ws (q x kpos), B = Vt (d x kpos) -> C[q][d]
        #pragma unroll
        for (int s = 0; s < 2; ++s) {
            bf16x8 wf = *(const bf16x8*)&Ws[wave * 16 + l15][s * 32 + kq];
            #pragma unroll
            for (int nb = 0; nb < 4; ++nb) {
                bf16x8 vf = *(const bf16x8*)&Vt[nb * 16 + l15][s * 32 + kq];
                oacc[nb] = __builtin_amdgcn_mfma_f32_16x16x32_bf16(
                    wf, vf, oacc[nb], 0, 0, 0);
            }
        }
    }

    #pragma unroll
    for (int nb = 0; nb < 4; ++nb)
        #pragma unroll
        for (int r = 0; r < 4; ++r) {
            float o = oacc[nb][r] * invl[r];
            AO[(size_t)(b * SS + qrow + r) * 2048 + h * 64 + nb * 16 + l15] =
                f2bf(o);
        }
}

// ---------------------------------------------------------------------------
extern "C" void kernel_launch(void* const* d_in, const int* in_sizes, int n_in,
                              void* d_out, int out_size, void* d_ws, size_t ws_size,
                              hipStream_t stream)
{
    const float* hidden    = (const float*)d_in[0];
    const float* Wq        = (const float*)d_in[2];
    const float* Wk        = (const float*)d_in[3];
    const float* Wv        = (const float*)d_in[4];
    const float* Wo        = (const float*)d_in[5];
    const float* bias_diag = (const float*)d_in[6];
    const float* soff      = (const float*)d_in[7];
    float* out = (float*)d_out;

    // Workspace aliasing (54.5 MB total, same footprint as R2):
    //  region A [0, 20.97M):  hidden_bf(8.39M)+WqkvT(12.58M)  --dead after QKV gemm-->
    //                         qk_bf(10.49M)+v_t(2.10M)
    //  region B [20.97M, 29.36M): WoT (8.39M)
    //  region C [29.36M, 54.53M): qkv fp32 (25.17M) --dead after v_transpose--> AO_bf(8.39M)
    char* wsb = (char*)d_ws;
    unsigned short* hidden_bf = (unsigned short*)wsb;
    unsigned short* WqkvT     = (unsigned short*)(wsb + (size_t)2048 * 2048 * 2);
    unsigned short* qk_bf     = (unsigned short*)wsb;
    unsigned short* v_t       = (unsigned short*)(wsb + (size_t)2048 * 2560 * 2);
    unsigned short* WoT       = (unsigned short*)(wsb + (size_t)20971520);
    float*          qkv       = (float*)(wsb + (size_t)29360128);
    unsigned short* AO_bf     = (unsigned short*)(wsb + (size_t)29360128);

    // 1. hidden -> bf16
    to_bf16<<<dim3(2048 * 2048 / 4 / 256), dim3(256), 0, stream>>>(hidden, hidden_bf);

    // 2. weight transposes
    transpose_to_bf16<<<dim3(64, 64), dim3(32, 8), 0, stream>>>(Wq, WqkvT, 2048, 2048);
    transpose_to_bf16<<<dim3(16, 64), dim3(32, 8), 0, stream>>>(Wk, WqkvT + (size_t)2048 * 2048, 512, 2048);
    transpose_to_bf16<<<dim3(16, 64), dim3(32, 8), 0, stream>>>(Wv, WqkvT + (size_t)2560 * 2048, 512, 2048);
    transpose_to_bf16<<<dim3(64, 64), dim3(32, 8), 0, stream>>>(Wo, WoT, 2048, 2048);

    // 3. fused QKV projection (fp32 out)
    gemm_bf16_bt<<<dim3(NQKV / 128, 2048 / 128), dim3(256), 0, stream>>>(
        hidden_bf, WqkvT, qkv, 2048, NQKV, 2048);

    // 4. RoPE q,k -> qk_bf (bf16); V transpose -> v_t (bf16)
    rope_convert<<<dim3(40, 256), dim3(256), 0, stream>>>(qkv, qk_bf);
    v_transpose<<<dim3(16, 32, 2), dim3(32, 8), 0, stream>>>(qkv, v_t);

    // 5. MFMA attention -> AO_bf
    attn_mfma<<<dim3(16, HH, BB), dim3(256), 0, stream>>>(
        qk_bf, v_t, bias_diag, soff, AO_bf);

    // 6. output projection
    gemm_bf16_bt<<<dim3(2048 / 128, 2048 / 128), dim3(256), 0, stream>>>(
        AO_bf, WoT, out, 2048, 2048, 2048);
}